// Round 1
// baseline (981.152 us; speedup 1.0000x reference)
//
#include <hip/hip_runtime.h>

#define B_    4
#define T_    4096
#define D_    1024
#define H_    16
#define DH_   64
#define KTOK  2048
#define MROWS (B_*KTOK)   // 8192

typedef unsigned short u16;
typedef __attribute__((ext_vector_type(8))) short short8;
typedef __attribute__((ext_vector_type(4))) float f32x4;
typedef __attribute__((ext_vector_type(4))) unsigned int u32x4;
typedef __attribute__((ext_vector_type(4))) unsigned short u16x4;

static __device__ __forceinline__ u16 f2bf(float f) {
  union { float f; unsigned int u; } a; a.f = f;
  unsigned int u = a.u;
  unsigned int r = (u + 0x7FFFu + ((u >> 16) & 1u)) >> 16;   // RNE
  return (u16)r;
}

static __device__ __forceinline__ void gld_lds16(const u16* g, u16* l) {
  __builtin_amdgcn_global_load_lds((__attribute__((address_space(1))) void*)g,
                                   (__attribute__((address_space(3))) void*)l, 16, 0, 0);
}

// ---------------- router: logits = x @ w_router, accumulate sum(logits^2) ----------------
__global__ void __launch_bounds__(256) router_kernel(const float* __restrict__ x,
    const float* __restrict__ wr, float* __restrict__ logits, float* __restrict__ auxacc)
{
  int tid = threadIdx.x; int lane = tid & 63, wave = tid >> 6;
  int row = blockIdx.x * 4 + wave;                 // 0 .. B*T-1
  const float* xr = x + (size_t)row * D_;
  float dot = 0.f;
#pragma unroll
  for (int j = 0; j < 4; j++) {
    int c = j * 256 + lane * 4;
    f32x4 xv = *(const f32x4*)(xr + c);
    f32x4 wv = *(const f32x4*)(wr + c);
    dot += xv[0]*wv[0] + xv[1]*wv[1] + xv[2]*wv[2] + xv[3]*wv[3];
  }
#pragma unroll
  for (int d = 1; d < 64; d <<= 1) dot += __shfl_xor(dot, d);
  __shared__ float red[4];
  if (lane == 0) { logits[row] = dot; red[wave] = dot; }
  __syncthreads();
  if (tid == 0) {
    float a = red[0]*red[0] + red[1]*red[1] + red[2]*red[2] + red[3]*red[3];
    atomicAdd(auxacc, a);
  }
}

__global__ void aux_fin(const float* __restrict__ acc, float* __restrict__ out)
{
  out[0] = acc[0] * (0.01f / (float)(B_ * T_));
}

// ---------------- rank: selected iff #{better} < KTOK ----------------
__global__ void __launch_bounds__(256) rank_kernel(const float* __restrict__ logits, int* __restrict__ mask)
{
  __shared__ float ll[T_];
  int b = blockIdx.y;
  int tid = threadIdx.x;
  const float* lg = logits + (size_t)b * T_;
  for (int j = tid; j < T_; j += 256) ll[j] = lg[j];
  __syncthreads();
  int t = blockIdx.x * 256 + tid;
  float my = ll[t];
  int rank = 0;
  for (int j = 0; j < T_; j += 4) {
    f32x4 lj = *(const f32x4*)&ll[j];
    rank += (lj[0] > my) || (lj[0] == my && (j+0) < t);
    rank += (lj[1] > my) || (lj[1] == my && (j+1) < t);
    rank += (lj[2] > my) || (lj[2] == my && (j+2) < t);
    rank += (lj[3] > my) || (lj[3] == my && (j+3) < t);
  }
  mask[(size_t)b * T_ + t] = (rank < KTOK) ? 1 : 0;
}

// ---------------- compact selected token ids (ascending) ----------------
__global__ void __launch_bounds__(64) compact_kernel(const int* __restrict__ mask, int* __restrict__ idx)
{
  int b = blockIdx.x; int lane = threadIdx.x;
  int base = 0;
  for (int c = 0; c < T_; c += 64) {
    int t = c + lane;
    int m = mask[(size_t)b * T_ + t];
    unsigned long long bal = __ballot(m != 0);
    int pref = __popcll(bal & ((1ull << lane) - 1ull));
    if (m) idx[b * KTOK + base + pref] = t;
    base += __popcll(bal);
  }
}

// ---------------- LayerNorm (optionally gathering rows of x via idx) ----------------
template<bool GATHER>
__global__ void __launch_bounds__(256) ln_kernel(const float* __restrict__ src,
    const int* __restrict__ idx, const float* __restrict__ g, const float* __restrict__ bb,
    float* __restrict__ xs_out, u16* __restrict__ hout)
{
  int row = blockIdx.x;
  int tid = threadIdx.x;
  const float* srow;
  if (GATHER) {
    int b = row >> 11, i = row & (KTOK - 1);
    int t = idx[b * KTOK + i];
    srow = src + ((size_t)b * T_ + t) * D_;
  } else {
    srow = src + (size_t)row * D_;
  }
  f32x4 v = *(const f32x4*)(srow + tid * 4);
  float s  = v[0] + v[1] + v[2] + v[3];
  float sq = v[0]*v[0] + v[1]*v[1] + v[2]*v[2] + v[3]*v[3];
#pragma unroll
  for (int d = 1; d < 64; d <<= 1) { s += __shfl_xor(s, d); sq += __shfl_xor(sq, d); }
  __shared__ float rs[4], rq[4];
  int lane = tid & 63, wave = tid >> 6;
  if (lane == 0) { rs[wave] = s; rq[wave] = sq; }
  __syncthreads();
  s  = rs[0] + rs[1] + rs[2] + rs[3];
  sq = rq[0] + rq[1] + rq[2] + rq[3];
  float mean = s * (1.0f / D_);
  float var  = sq * (1.0f / D_) - mean * mean;
  float rstd = rsqrtf(var + 1e-5f);
  f32x4 gg = *(const f32x4*)(g + tid * 4);
  f32x4 bv = *(const f32x4*)(bb + tid * 4);
  if (GATHER) *(f32x4*)(xs_out + (size_t)row * D_ + tid * 4) = v;
  u16x4 o;
#pragma unroll
  for (int j = 0; j < 4; j++) o[j] = f2bf((v[j] - mean) * rstd * gg[j] + bv[j]);
  *(u16x4*)(hout + (size_t)row * D_ + tid * 4) = o;
}

// ---------------- fp32 -> bf16 weight convert ----------------
__global__ void __launch_bounds__(256) f2bf_kernel(const float* __restrict__ s, u16* __restrict__ d, int n)
{
  int i = (blockIdx.x * 256 + threadIdx.x) * 4;
  if (i < n) {
    f32x4 v = *(const f32x4*)(s + i);
    u16x4 o; o[0]=f2bf(v[0]); o[1]=f2bf(v[1]); o[2]=f2bf(v[2]); o[3]=f2bf(v[3]);
    *(u16x4*)(d + i) = o;
  }
}

// ---------------- GEMM: C[M,N] = A[M,K](bf16) @ W[N,K]^T(bf16) + bias, fused epilogues --------
// EPI 0: write bf16 to Cb
// EPI 1: v += xs (fp32 residual), write fp32 to xs (in place)
// EPI 2: exact gelu, write bf16 to Cb
// EPI 3: v += xs residual, scatter-write fp32 rows into outf at token idx
template<int EPI>
__global__ void __launch_bounds__(256, 2) gemm_bt(
    const u16* __restrict__ A, const u16* __restrict__ W,
    const float* __restrict__ bias, float* __restrict__ xs,
    u16* __restrict__ Cb, float* __restrict__ outf,
    const int* __restrict__ idx, int M, int N, int K)
{
  __shared__ u16 As[128 * 32];
  __shared__ u16 Ws[128 * 32];
  const int tid = threadIdx.x;
  const int lane = tid & 63, wave = tid >> 6;
  const int wm = wave >> 1, wn = wave & 1;
  const int m16 = lane & 15, quad = lane >> 4;

  const size_t arow0 = (size_t)blockIdx.y * 128;
  const size_t wrow0 = (size_t)blockIdx.x * 128;
  const int r4 = lane >> 2, c8 = (lane & 3) * 8;

  const u16* ag0 = A + (arow0 + wave * 16 + r4) * (size_t)K + c8;
  const u16* ag1 = ag0 + (size_t)64 * K;
  const u16* wg0 = W + (wrow0 + wave * 16 + r4) * (size_t)K + c8;
  const u16* wg1 = wg0 + (size_t)64 * K;
  u16* la0 = As + (wave * 16) * 32;
  u16* la1 = As + (64 + wave * 16) * 32;
  u16* lw0 = Ws + (wave * 16) * 32;
  u16* lw1 = Ws + (64 + wave * 16) * 32;

  f32x4 acc[4][4];
#pragma unroll
  for (int i = 0; i < 4; i++)
#pragma unroll
    for (int j = 0; j < 4; j++) acc[i][j] = (f32x4)0.0f;

  for (int k0 = 0; k0 < K; k0 += 32) {
    gld_lds16(ag0 + k0, la0);
    gld_lds16(ag1 + k0, la1);
    gld_lds16(wg0 + k0, lw0);
    gld_lds16(wg1 + k0, lw1);
    __syncthreads();
    short8 af[4], wf[4];
#pragma unroll
    for (int mt = 0; mt < 4; mt++)
      af[mt] = *(const short8*)(As + (wm * 64 + mt * 16 + m16) * 32 + quad * 8);
#pragma unroll
    for (int nt = 0; nt < 4; nt++)
      wf[nt] = *(const short8*)(Ws + (wn * 64 + nt * 16 + m16) * 32 + quad * 8);
#pragma unroll
    for (int mt = 0; mt < 4; mt++)
#pragma unroll
      for (int nt = 0; nt < 4; nt++)
        acc[mt][nt] = __builtin_amdgcn_mfma_f32_16x16x32_bf16(af[mt], wf[nt], acc[mt][nt], 0, 0, 0);
    __syncthreads();
  }

#pragma unroll
  for (int mt = 0; mt < 4; mt++) {
#pragma unroll
    for (int nt = 0; nt < 4; nt++) {
      f32x4 a = acc[mt][nt];
      size_t col = wrow0 + wn * 64 + nt * 16 + m16;
      float bvv = bias[col];
#pragma unroll
      for (int r = 0; r < 4; r++) {
        size_t row = arow0 + wm * 64 + mt * 16 + quad * 4 + r;
        float v = a[r] + bvv;
        if (EPI == 0) {
          Cb[row * (size_t)N + col] = f2bf(v);
        } else if (EPI == 1) {
          size_t o = row * (size_t)N + col;
          xs[o] = xs[o] + v;
        } else if (EPI == 2) {
          float gv = 0.5f * v * (1.0f + erff(v * 0.70710678118654752f));
          Cb[row * (size_t)N + col] = f2bf(gv);
        } else {
          int b = (int)(row >> 11);
          int i = (int)(row & (KTOK - 1));
          int t = idx[b * KTOK + i];
          float vv = xs[row * (size_t)D_ + col] + v;
          outf[((size_t)b * T_ + t) * D_ + col] = vv;
        }
      }
    }
  }
}

// ---------------- flash attention: per (b,h), 64-row Q tile per block ----------------
__global__ void __launch_bounds__(256, 2) attn_kernel(const u16* __restrict__ qkv,
                                                      u16* __restrict__ obuf)
{
  __shared__ u16 Ks[64 * 64];     // [key][dh]
  __shared__ u16 Vt[64][88];      // [dh][key], padded
  __shared__ u16 Ps[4][16 * 64];  // per-wave P, [qrow][key]

  const int tid = threadIdx.x;
  const int lane = tid & 63, wave = tid >> 6;
  const int m16 = lane & 15, quad = lane >> 4;
  const int bh = blockIdx.y;
  const int b = bh >> 4, h = bh & 15;
  const int q0 = blockIdx.x * 64 + wave * 16;

  const u16* base = qkv + ((size_t)b * KTOK) * (3 * D_) + h * DH_;
  const u16* qrow = base + (size_t)(q0 + m16) * (3 * D_);
  short8 qf0 = *(const short8*)(qrow + quad * 8);
  short8 qf1 = *(const short8*)(qrow + 32 + quad * 8);

  f32x4 oacc[4];
#pragma unroll
  for (int nt = 0; nt < 4; nt++) oacc[nt] = (f32x4)0.0f;
  float mrow[4] = {-__builtin_inff(), -__builtin_inff(), -__builtin_inff(), -__builtin_inff()};
  float lrow[4] = {0.f, 0.f, 0.f, 0.f};

  for (int tk = 0; tk < KTOK; tk += 64) {
    __syncthreads();
    {
      int key = tid >> 2;
      int dof = (tid & 3) * 16;
      const u16* krow = base + (size_t)(tk + key) * (3 * D_) + D_ + dof;   // K at +D
      *(u32x4*)&Ks[key * 64 + dof]     = *(const u32x4*)krow;
      *(u32x4*)&Ks[key * 64 + dof + 8] = *(const u32x4*)(krow + 8);
      const u16* vrow = krow + D_;                                         // V at +2D
      u16 tmp[16] __attribute__((aligned(16)));
      *(u32x4*)&tmp[0] = *(const u32x4*)vrow;
      *(u32x4*)&tmp[8] = *(const u32x4*)(vrow + 8);
#pragma unroll
      for (int j = 0; j < 16; j++) Vt[dof + j][key] = tmp[j];
    }
    __syncthreads();

    f32x4 sacc[4];
#pragma unroll
    for (int nt = 0; nt < 4; nt++) sacc[nt] = (f32x4)0.0f;
#pragma unroll
    for (int nt = 0; nt < 4; nt++) {
      short8 kf0 = *(const short8*)(Ks + (nt * 16 + m16) * 64 + quad * 8);
      short8 kf1 = *(const short8*)(Ks + (nt * 16 + m16) * 64 + 32 + quad * 8);
      sacc[nt] = __builtin_amdgcn_mfma_f32_16x16x32_bf16(qf0, kf0, sacc[nt], 0, 0, 0);
      sacc[nt] = __builtin_amdgcn_mfma_f32_16x16x32_bf16(qf1, kf1, sacc[nt], 0, 0, 0);
    }
#pragma unroll
    for (int nt = 0; nt < 4; nt++) sacc[nt] *= 0.125f;   // 1/sqrt(64)

#pragma unroll
    for (int r = 0; r < 4; r++) {
      float mx = fmaxf(fmaxf(sacc[0][r], sacc[1][r]), fmaxf(sacc[2][r], sacc[3][r]));
#pragma unroll
      for (int d = 1; d < 16; d <<= 1) mx = fmaxf(mx, __shfl_xor(mx, d));
      float mnew = fmaxf(mrow[r], mx);
      float alpha = __expf(mrow[r] - mnew);
      mrow[r] = mnew;
      float rsum = 0.f;
#pragma unroll
      for (int nt = 0; nt < 4; nt++) {
        float p = __expf(sacc[nt][r] - mnew);
        sacc[nt][r] = p;
        rsum += p;
      }
#pragma unroll
      for (int d = 1; d < 16; d <<= 1) rsum += __shfl_xor(rsum, d);
      lrow[r] = lrow[r] * alpha + rsum;
#pragma unroll
      for (int nt = 0; nt < 4; nt++) oacc[nt][r] *= alpha;
    }

#pragma unroll
    for (int nt = 0; nt < 4; nt++)
#pragma unroll
      for (int r = 0; r < 4; r++)
        Ps[wave][(quad * 4 + r) * 64 + nt * 16 + m16] = f2bf(sacc[nt][r]);

    short8 pa0 = *(const short8*)(&Ps[wave][m16 * 64 + quad * 8]);
    short8 pa1 = *(const short8*)(&Ps[wave][m16 * 64 + 32 + quad * 8]);
#pragma unroll
    for (int nt = 0; nt < 4; nt++) {
      short8 vf0 = *(const short8*)(&Vt[nt * 16 + m16][quad * 8]);
      short8 vf1 = *(const short8*)(&Vt[nt * 16 + m16][32 + quad * 8]);
      oacc[nt] = __builtin_amdgcn_mfma_f32_16x16x32_bf16(pa0, vf0, oacc[nt], 0, 0, 0);
      oacc[nt] = __builtin_amdgcn_mfma_f32_16x16x32_bf16(pa1, vf1, oacc[nt], 0, 0, 0);
    }
  }

#pragma unroll
  for (int nt = 0; nt < 4; nt++)
#pragma unroll
    for (int r = 0; r < 4; r++) {
      int qq = q0 + quad * 4 + r;
      float v = oacc[nt][r] / lrow[r];
      obuf[((size_t)b * KTOK + qq) * D_ + h * DH_ + nt * 16 + m16] = f2bf(v);
    }
}

// ---------------- launch ----------------
extern "C" void kernel_launch(void* const* d_in, const int* in_sizes, int n_in,
                              void* d_out, int out_size, void* d_ws, size_t ws_size,
                              hipStream_t stream)
{
  (void)in_sizes; (void)n_in; (void)out_size; (void)ws_size;
  const float* x          = (const float*)d_in[0];
  const float* w_router   = (const float*)d_in[1];
  const float* in_proj_w  = (const float*)d_in[2];
  const float* in_proj_b  = (const float*)d_in[3];
  const float* out_proj_w = (const float*)d_in[4];
  const float* out_proj_b = (const float*)d_in[5];
  const float* w1         = (const float*)d_in[6];
  const float* b1         = (const float*)d_in[7];
  const float* w2         = (const float*)d_in[8];
  const float* b2         = (const float*)d_in[9];
  const float* ln1g       = (const float*)d_in[10];
  const float* ln1b       = (const float*)d_in[11];
  const float* ln2g       = (const float*)d_in[12];
  const float* ln2b       = (const float*)d_in[13];
  float* out = (float*)d_out;

  char* w = (char*)d_ws;
  auto alloc = [&](size_t bytes) -> char* {
    char* p = w; w += (bytes + 255) & ~(size_t)255; return p;
  };
  float* logits = (float*)alloc((size_t)B_ * T_ * 4);
  int*   mask   = (int*)  alloc((size_t)B_ * T_ * 4);
  int*   idx    = (int*)  alloc((size_t)B_ * KTOK * 4);
  float* auxacc = (float*)alloc(256);
  u16* inpw  = (u16*)alloc((size_t)3 * D_ * D_ * 2);
  u16* outpw = (u16*)alloc((size_t)D_ * D_ * 2);
  u16* w1b   = (u16*)alloc((size_t)4 * D_ * D_ * 2);
  u16* w2b   = (u16*)alloc((size_t)4 * D_ * D_ * 2);
  float* xs  = (float*)alloc((size_t)MROWS * D_ * 4);
  u16* hbuf  = (u16*)alloc((size_t)MROWS * D_ * 2);
  char* region = alloc((size_t)MROWS * 4 * D_ * 2);      // 64 MB: qkv(48)+obuf(16), reused by ff
  u16* qkvb = (u16*)region;
  u16* obuf = (u16*)(region + (size_t)MROWS * 3 * D_ * 2);
  u16* ffb  = (u16*)region;

  // pass-through copy of x into out; processed rows overwritten by ff2 scatter
  hipMemcpyAsync(d_out, (const void*)x, (size_t)B_ * T_ * D_ * 4, hipMemcpyDeviceToDevice, stream);
  hipMemsetAsync(auxacc, 0, 4, stream);

  router_kernel<<<B_ * T_ / 4, 256, 0, stream>>>(x, w_router, logits, auxacc);
  aux_fin<<<1, 1, 0, stream>>>(auxacc, out + (size_t)B_ * T_ * D_);
  rank_kernel<<<dim3(T_ / 256, B_), 256, 0, stream>>>(logits, mask);
  compact_kernel<<<B_, 64, 0, stream>>>(mask, idx);
  ln_kernel<true><<<MROWS, 256, 0, stream>>>(x, idx, ln1g, ln1b, xs, hbuf);

  f2bf_kernel<<<(3 * D_ * D_ / 4) / 256, 256, 0, stream>>>(in_proj_w, inpw, 3 * D_ * D_);
  f2bf_kernel<<<(D_ * D_ / 4) / 256, 256, 0, stream>>>(out_proj_w, outpw, D_ * D_);
  f2bf_kernel<<<(4 * D_ * D_ / 4) / 256, 256, 0, stream>>>(w1, w1b, 4 * D_ * D_);
  f2bf_kernel<<<(4 * D_ * D_ / 4) / 256, 256, 0, stream>>>(w2, w2b, 4 * D_ * D_);

  gemm_bt<0><<<dim3(3 * D_ / 128, MROWS / 128), 256, 0, stream>>>(
      hbuf, inpw, in_proj_b, nullptr, qkvb, nullptr, nullptr, MROWS, 3 * D_, D_);
  attn_kernel<<<dim3(KTOK / 64, B_ * H_), 256, 0, stream>>>(qkvb, obuf);
  gemm_bt<1><<<dim3(D_ / 128, MROWS / 128), 256, 0, stream>>>(
      obuf, outpw, out_proj_b, xs, nullptr, nullptr, nullptr, MROWS, D_, D_);
  ln_kernel<false><<<MROWS, 256, 0, stream>>>(xs, nullptr, ln2g, ln2b, nullptr, hbuf);
  gemm_bt<2><<<dim3(4 * D_ / 128, MROWS / 128), 256, 0, stream>>>(
      hbuf, w1b, b1, nullptr, ffb, nullptr, nullptr, MROWS, 4 * D_, D_);
  gemm_bt<3><<<dim3(D_ / 128, MROWS / 128), 256, 0, stream>>>(
      ffb, w2b, b2, xs, nullptr, out, idx, MROWS, D_, 4 * D_);
}

// Round 2
// 881.952 us; speedup vs baseline: 1.1125x; 1.1125x over previous
//
#include <hip/hip_runtime.h>

#define B_    4
#define T_    4096
#define D_    1024
#define H_    16
#define DH_   64
#define KTOK  2048
#define MROWS (B_*KTOK)   // 8192

typedef unsigned short u16;
typedef __attribute__((ext_vector_type(8))) short short8;
typedef __attribute__((ext_vector_type(4))) float f32x4;
typedef __attribute__((ext_vector_type(4))) unsigned int u32x4;
typedef __attribute__((ext_vector_type(4))) unsigned short u16x4;

static __device__ __forceinline__ u16 f2bf(float f) {
  union { float f; unsigned int u; } a; a.f = f;
  unsigned int u = a.u;
  unsigned int r = (u + 0x7FFFu + ((u >> 16) & 1u)) >> 16;   // RNE
  return (u16)r;
}

static __device__ __forceinline__ void gld_lds16(const u16* g, u16* l) {
  __builtin_amdgcn_global_load_lds((__attribute__((address_space(1))) void*)g,
                                   (__attribute__((address_space(3))) void*)l, 16, 0, 0);
}

template<int N>
static __device__ __forceinline__ float dpp_ror(float x) {
  int r = __builtin_amdgcn_update_dpp(0, __builtin_bit_cast(int, x), 0x120 + N, 0xf, 0xf, true);
  return __builtin_bit_cast(float, r);
}

// ---------------- router: logits = x @ w_router, accumulate sum(logits^2) ----------------
__global__ void __launch_bounds__(256) router_kernel(const float* __restrict__ x,
    const float* __restrict__ wr, float* __restrict__ logits, float* __restrict__ auxacc)
{
  int tid = threadIdx.x; int lane = tid & 63, wave = tid >> 6;
  int row = blockIdx.x * 4 + wave;                 // 0 .. B*T-1
  const float* xr = x + (size_t)row * D_;
  float dot = 0.f;
#pragma unroll
  for (int j = 0; j < 4; j++) {
    int c = j * 256 + lane * 4;
    f32x4 xv = *(const f32x4*)(xr + c);
    f32x4 wv = *(const f32x4*)(wr + c);
    dot += xv[0]*wv[0] + xv[1]*wv[1] + xv[2]*wv[2] + xv[3]*wv[3];
  }
#pragma unroll
  for (int d = 1; d < 64; d <<= 1) dot += __shfl_xor(dot, d);
  __shared__ float red[4];
  if (lane == 0) { logits[row] = dot; red[wave] = dot; }
  __syncthreads();
  if (tid == 0) {
    float a = red[0]*red[0] + red[1]*red[1] + red[2]*red[2] + red[3]*red[3];
    atomicAdd(auxacc, a);
  }
}

__global__ void aux_fin(const float* __restrict__ acc, float* __restrict__ out)
{
  out[0] = acc[0] * (0.01f / (float)(B_ * T_));
}

// ---------------- rank: selected iff #{better} < KTOK ----------------
__global__ void __launch_bounds__(256) rank_kernel(const float* __restrict__ logits, int* __restrict__ mask)
{
  __shared__ float ll[T_];
  int b = blockIdx.y;
  int tid = threadIdx.x;
  const float* lg = logits + (size_t)b * T_;
  for (int j = tid; j < T_; j += 256) ll[j] = lg[j];
  __syncthreads();
  int t = blockIdx.x * 256 + tid;
  float my = ll[t];
  int rank = 0;
  for (int j = 0; j < T_; j += 4) {
    f32x4 lj = *(const f32x4*)&ll[j];
    rank += (lj[0] > my) || (lj[0] == my && (j+0) < t);
    rank += (lj[1] > my) || (lj[1] == my && (j+1) < t);
    rank += (lj[2] > my) || (lj[2] == my && (j+2) < t);
    rank += (lj[3] > my) || (lj[3] == my && (j+3) < t);
  }
  mask[(size_t)b * T_ + t] = (rank < KTOK) ? 1 : 0;
}

// ---------------- compact selected token ids (ascending) ----------------
__global__ void __launch_bounds__(64) compact_kernel(const int* __restrict__ mask, int* __restrict__ idx)
{
  int b = blockIdx.x; int lane = threadIdx.x;
  int base = 0;
  for (int c = 0; c < T_; c += 64) {
    int t = c + lane;
    int m = mask[(size_t)b * T_ + t];
    unsigned long long bal = __ballot(m != 0);
    int pref = __popcll(bal & ((1ull << lane) - 1ull));
    if (m) idx[b * KTOK + base + pref] = t;
    base += __popcll(bal);
  }
}

// ---------------- LayerNorm (optionally gathering rows of x via idx) ----------------
template<bool GATHER>
__global__ void __launch_bounds__(256) ln_kernel(const float* __restrict__ src,
    const int* __restrict__ idx, const float* __restrict__ g, const float* __restrict__ bb,
    float* __restrict__ xs_out, u16* __restrict__ hout)
{
  int row = blockIdx.x;
  int tid = threadIdx.x;
  const float* srow;
  if (GATHER) {
    int b = row >> 11, i = row & (KTOK - 1);
    int t = idx[b * KTOK + i];
    srow = src + ((size_t)b * T_ + t) * D_;
  } else {
    srow = src + (size_t)row * D_;
  }
  f32x4 v = *(const f32x4*)(srow + tid * 4);
  float s  = v[0] + v[1] + v[2] + v[3];
  float sq = v[0]*v[0] + v[1]*v[1] + v[2]*v[2] + v[3]*v[3];
#pragma unroll
  for (int d = 1; d < 64; d <<= 1) { s += __shfl_xor(s, d); sq += __shfl_xor(sq, d); }
  __shared__ float rs[4], rq[4];
  int lane = tid & 63, wave = tid >> 6;
  if (lane == 0) { rs[wave] = s; rq[wave] = sq; }
  __syncthreads();
  s  = rs[0] + rs[1] + rs[2] + rs[3];
  sq = rq[0] + rq[1] + rq[2] + rq[3];
  float mean = s * (1.0f / D_);
  float var  = sq * (1.0f / D_) - mean * mean;
  float rstd = rsqrtf(var + 1e-5f);
  f32x4 gg = *(const f32x4*)(g + tid * 4);
  f32x4 bv = *(const f32x4*)(bb + tid * 4);
  if (GATHER) *(f32x4*)(xs_out + (size_t)row * D_ + tid * 4) = v;
  u16x4 o;
#pragma unroll
  for (int j = 0; j < 4; j++) o[j] = f2bf((v[j] - mean) * rstd * gg[j] + bv[j]);
  *(u16x4*)(hout + (size_t)row * D_ + tid * 4) = o;
}

// ---------------- fp32 -> bf16 weight convert ----------------
__global__ void __launch_bounds__(256) f2bf_kernel(const float* __restrict__ s, u16* __restrict__ d, int n)
{
  int i = (blockIdx.x * 256 + threadIdx.x) * 4;
  if (i < n) {
    f32x4 v = *(const f32x4*)(s + i);
    u16x4 o; o[0]=f2bf(v[0]); o[1]=f2bf(v[1]); o[2]=f2bf(v[2]); o[3]=f2bf(v[3]);
    *(u16x4*)(d + i) = o;
  }
}

// ---------------- GEMM: C[M,N] = A[M,K](bf16) @ W[N,K]^T(bf16) + bias, fused epilogues --------
template<int EPI>
__global__ void __launch_bounds__(256, 2) gemm_bt(
    const u16* __restrict__ A, const u16* __restrict__ W,
    const float* __restrict__ bias, float* __restrict__ xs,
    u16* __restrict__ Cb, float* __restrict__ outf,
    const int* __restrict__ idx, int M, int N, int K)
{
  __shared__ u16 As[128 * 32];
  __shared__ u16 Ws[128 * 32];
  const int tid = threadIdx.x;
  const int lane = tid & 63, wave = tid >> 6;
  const int wm = wave >> 1, wn = wave & 1;
  const int m16 = lane & 15, quad = lane >> 4;

  const size_t arow0 = (size_t)blockIdx.y * 128;
  const size_t wrow0 = (size_t)blockIdx.x * 128;
  const int r4 = lane >> 2, c8 = (lane & 3) * 8;

  const u16* ag0 = A + (arow0 + wave * 16 + r4) * (size_t)K + c8;
  const u16* ag1 = ag0 + (size_t)64 * K;
  const u16* wg0 = W + (wrow0 + wave * 16 + r4) * (size_t)K + c8;
  const u16* wg1 = wg0 + (size_t)64 * K;
  u16* la0 = As + (wave * 16) * 32;
  u16* la1 = As + (64 + wave * 16) * 32;
  u16* lw0 = Ws + (wave * 16) * 32;
  u16* lw1 = Ws + (64 + wave * 16) * 32;

  f32x4 acc[4][4];
#pragma unroll
  for (int i = 0; i < 4; i++)
#pragma unroll
    for (int j = 0; j < 4; j++) acc[i][j] = (f32x4)0.0f;

  for (int k0 = 0; k0 < K; k0 += 32) {
    gld_lds16(ag0 + k0, la0);
    gld_lds16(ag1 + k0, la1);
    gld_lds16(wg0 + k0, lw0);
    gld_lds16(wg1 + k0, lw1);
    __syncthreads();
    short8 af[4], wf[4];
#pragma unroll
    for (int mt = 0; mt < 4; mt++)
      af[mt] = *(const short8*)(As + (wm * 64 + mt * 16 + m16) * 32 + quad * 8);
#pragma unroll
    for (int nt = 0; nt < 4; nt++)
      wf[nt] = *(const short8*)(Ws + (wn * 64 + nt * 16 + m16) * 32 + quad * 8);
#pragma unroll
    for (int mt = 0; mt < 4; mt++)
#pragma unroll
      for (int nt = 0; nt < 4; nt++)
        acc[mt][nt] = __builtin_amdgcn_mfma_f32_16x16x32_bf16(af[mt], wf[nt], acc[mt][nt], 0, 0, 0);
    __syncthreads();
  }

#pragma unroll
  for (int mt = 0; mt < 4; mt++) {
#pragma unroll
    for (int nt = 0; nt < 4; nt++) {
      f32x4 a = acc[mt][nt];
      size_t col = wrow0 + wn * 64 + nt * 16 + m16;
      float bvv = bias[col];
#pragma unroll
      for (int r = 0; r < 4; r++) {
        size_t row = arow0 + wm * 64 + mt * 16 + quad * 4 + r;
        float v = a[r] + bvv;
        if (EPI == 0) {
          Cb[row * (size_t)N + col] = f2bf(v);
        } else if (EPI == 1) {
          size_t o = row * (size_t)N + col;
          xs[o] = xs[o] + v;
        } else if (EPI == 2) {
          float gv = 0.5f * v * (1.0f + erff(v * 0.70710678118654752f));
          Cb[row * (size_t)N + col] = f2bf(gv);
        } else {
          int b = (int)(row >> 11);
          int i = (int)(row & (KTOK - 1));
          int t = idx[b * KTOK + i];
          float vv = xs[row * (size_t)D_ + col] + v;
          outf[((size_t)b * T_ + t) * D_ + col] = vv;
        }
      }
    }
  }
}

// ---------------- flash attention v2: 128-row Q tile per block, conflict-free LDS ----------------
// Ks: [key][dh]   stride 72 u16 (padded)
// Vt: [dh][key]   stride 88 u16, b64-block XOR swizzle kb^((dh>>2)&14)
// Ps: per-wave [qrow 0..31][key] stride 72 u16, block swizzle p=(nt+(row>>2))&3
__global__ void __launch_bounds__(256, 4) attn_kernel(const u16* __restrict__ qkv,
                                                      u16* __restrict__ obuf)
{
  __shared__ u16 Ks[64 * 72];        // 9216 B
  __shared__ u16 Vt[64 * 88];        // 11264 B
  __shared__ u16 Ps[4][32 * 72];     // 18432 B

  const int tid = threadIdx.x;
  const int lane = tid & 63, wave = tid >> 6;
  const int m16 = lane & 15, quad = lane >> 4;
  const int bh = blockIdx.y;
  const int b = bh >> 4, h = bh & 15;
  const int q0 = blockIdx.x * 128 + wave * 32;     // this wave: q0..q0+31 (two 16-row frags)

  const u16* base = qkv + ((size_t)b * KTOK) * (3 * D_) + h * DH_;

  // Q fragments (loaded once)
  short8 qf[2][2];
#pragma unroll
  for (int qh = 0; qh < 2; qh++) {
    const u16* qrow = base + (size_t)(q0 + qh * 16 + m16) * (3 * D_);
    qf[qh][0] = *(const short8*)(qrow + quad * 8);
    qf[qh][1] = *(const short8*)(qrow + 32 + quad * 8);
  }

  f32x4 oacc[2][4];
#pragma unroll
  for (int qh = 0; qh < 2; qh++)
#pragma unroll
    for (int nt = 0; nt < 4; nt++) oacc[qh][nt] = (f32x4)0.0f;
  float mrow[2][4], lrow[2][4];
#pragma unroll
  for (int qh = 0; qh < 2; qh++)
#pragma unroll
    for (int r = 0; r < 4; r++) { mrow[qh][r] = -__builtin_inff(); lrow[qh][r] = 0.f; }

  for (int tk = 0; tk < KTOK; tk += 64) {
    __syncthreads();
    // ---- stage K: 256 threads, key=tid>>2, dof=(tid&3)*16 ----
    {
      int key = tid >> 2, dof = (tid & 3) * 16;
      const u16* krow = base + (size_t)(tk + key) * (3 * D_) + D_ + dof;
      *(u32x4*)&Ks[key * 72 + dof]     = *(const u32x4*)krow;
      *(u32x4*)&Ks[key * 72 + dof + 8] = *(const u32x4*)(krow + 8);
    }
    // ---- stage V transposed: wave w loads keys tk+16w..+15, lane = dh ----
    {
      u16 vv[16];
      const u16* vp = base + (size_t)(tk + wave * 16) * (3 * D_) + 2 * D_ + lane;
#pragma unroll
      for (int i = 0; i < 16; i++) vv[i] = vp[(size_t)i * 3 * D_];
      int sw = (lane >> 2) & 14;
#pragma unroll
      for (int c = 0; c < 4; c++) {
        int kb = wave * 4 + c;
        u16x4 pk; pk[0] = vv[4*c]; pk[1] = vv[4*c+1]; pk[2] = vv[4*c+2]; pk[3] = vv[4*c+3];
        *(u16x4*)&Vt[lane * 88 + (kb ^ sw) * 4] = pk;
      }
    }
    __syncthreads();

    // ---- S = Q K^T (rows=q, cols=key) ----
    f32x4 sacc[2][4];
#pragma unroll
    for (int qh = 0; qh < 2; qh++)
#pragma unroll
      for (int nt = 0; nt < 4; nt++) sacc[qh][nt] = (f32x4)0.0f;
#pragma unroll
    for (int nt = 0; nt < 4; nt++) {
      short8 kf0 = *(const short8*)&Ks[(nt * 16 + m16) * 72 + quad * 8];
      short8 kf1 = *(const short8*)&Ks[(nt * 16 + m16) * 72 + 32 + quad * 8];
#pragma unroll
      for (int qh = 0; qh < 2; qh++) {
        sacc[qh][nt] = __builtin_amdgcn_mfma_f32_16x16x32_bf16(qf[qh][0], kf0, sacc[qh][nt], 0, 0, 0);
        sacc[qh][nt] = __builtin_amdgcn_mfma_f32_16x16x32_bf16(qf[qh][1], kf1, sacc[qh][nt], 0, 0, 0);
      }
    }

    // ---- online softmax (DPP row_ror reductions over the 16 m16 lanes) ----
#pragma unroll
    for (int qh = 0; qh < 2; qh++) {
#pragma unroll
      for (int r = 0; r < 4; r++) {
        float s0 = sacc[qh][0][r] * 0.125f;
        float s1 = sacc[qh][1][r] * 0.125f;
        float s2 = sacc[qh][2][r] * 0.125f;
        float s3 = sacc[qh][3][r] * 0.125f;
        float mx = fmaxf(fmaxf(s0, s1), fmaxf(s2, s3));
        mx = fmaxf(mx, dpp_ror<1>(mx));
        mx = fmaxf(mx, dpp_ror<2>(mx));
        mx = fmaxf(mx, dpp_ror<4>(mx));
        mx = fmaxf(mx, dpp_ror<8>(mx));
        float mnew = fmaxf(mrow[qh][r], mx);
        float alpha = __expf(mrow[qh][r] - mnew);
        mrow[qh][r] = mnew;
        float p0 = __expf(s0 - mnew);
        float p1 = __expf(s1 - mnew);
        float p2 = __expf(s2 - mnew);
        float p3 = __expf(s3 - mnew);
        float rs = (p0 + p1) + (p2 + p3);
        rs += dpp_ror<1>(rs);
        rs += dpp_ror<2>(rs);
        rs += dpp_ror<4>(rs);
        rs += dpp_ror<8>(rs);
        lrow[qh][r] = lrow[qh][r] * alpha + rs;
        sacc[qh][0][r] = p0; sacc[qh][1][r] = p1; sacc[qh][2][r] = p2; sacc[qh][3][r] = p3;
#pragma unroll
        for (int nt = 0; nt < 4; nt++) oacc[qh][nt][r] *= alpha;
      }
    }

    // ---- P -> LDS (C-layout rows quad*4+r, swizzled block position, conflict-free) ----
#pragma unroll
    for (int nt = 0; nt < 4; nt++) {
      int p = (nt + quad) & 3;     // (nt + (row>>2)) & 3, row>>2 = qh*4+quad, qh*4 == 0 mod 4
#pragma unroll
      for (int qh = 0; qh < 2; qh++)
#pragma unroll
        for (int r = 0; r < 4; r++)
          Ps[wave][(qh * 16 + quad * 4 + r) * 72 + p * 16 + m16] = f2bf(sacc[qh][nt][r]);
    }

    // ---- P A-fragments back from LDS ----
    short8 pa[2][2];
#pragma unroll
    for (int qh = 0; qh < 2; qh++)
#pragma unroll
      for (int c = 0; c < 2; c++) {
        int kb = 2 * c + (quad >> 1);
        int p = (kb + (m16 >> 2)) & 3;
        pa[qh][c] = *(const short8*)&Ps[wave][(qh * 16 + m16) * 72 + p * 16 + (quad & 1) * 8];
      }

    // ---- O += P V ----
#pragma unroll
    for (int nt = 0; nt < 4; nt++) {
      int dh = nt * 16 + m16;
      int sw = (dh >> 2) & 14;
      short8 vf0 = *(const short8*)&Vt[dh * 88 + ((2 * quad) ^ sw) * 4];
      short8 vf1 = *(const short8*)&Vt[dh * 88 + ((8 + 2 * quad) ^ sw) * 4];
#pragma unroll
      for (int qh = 0; qh < 2; qh++) {
        oacc[qh][nt] = __builtin_amdgcn_mfma_f32_16x16x32_bf16(pa[qh][0], vf0, oacc[qh][nt], 0, 0, 0);
        oacc[qh][nt] = __builtin_amdgcn_mfma_f32_16x16x32_bf16(pa[qh][1], vf1, oacc[qh][nt], 0, 0, 0);
      }
    }
  }

  // ---- epilogue ----
#pragma unroll
  for (int qh = 0; qh < 2; qh++)
#pragma unroll
    for (int nt = 0; nt < 4; nt++)
#pragma unroll
      for (int r = 0; r < 4; r++) {
        int qq = q0 + qh * 16 + quad * 4 + r;
        float v = oacc[qh][nt][r] / lrow[qh][r];
        obuf[((size_t)b * KTOK + qq) * D_ + h * DH_ + nt * 16 + m16] = f2bf(v);
      }
}

// ---------------- launch ----------------
extern "C" void kernel_launch(void* const* d_in, const int* in_sizes, int n_in,
                              void* d_out, int out_size, void* d_ws, size_t ws_size,
                              hipStream_t stream)
{
  (void)in_sizes; (void)n_in; (void)out_size; (void)ws_size;
  const float* x          = (const float*)d_in[0];
  const float* w_router   = (const float*)d_in[1];
  const float* in_proj_w  = (const float*)d_in[2];
  const float* in_proj_b  = (const float*)d_in[3];
  const float* out_proj_w = (const float*)d_in[4];
  const float* out_proj_b = (const float*)d_in[5];
  const float* w1         = (const float*)d_in[6];
  const float* b1         = (const float*)d_in[7];
  const float* w2         = (const float*)d_in[8];
  const float* b2         = (const float*)d_in[9];
  const float* ln1g       = (const float*)d_in[10];
  const float* ln1b       = (const float*)d_in[11];
  const float* ln2g       = (const float*)d_in[12];
  const float* ln2b       = (const float*)d_in[13];
  float* out = (float*)d_out;

  char* w = (char*)d_ws;
  auto alloc = [&](size_t bytes) -> char* {
    char* p = w; w += (bytes + 255) & ~(size_t)255; return p;
  };
  float* logits = (float*)alloc((size_t)B_ * T_ * 4);
  int*   mask   = (int*)  alloc((size_t)B_ * T_ * 4);
  int*   idx    = (int*)  alloc((size_t)B_ * KTOK * 4);
  float* auxacc = (float*)alloc(256);
  u16* inpw  = (u16*)alloc((size_t)3 * D_ * D_ * 2);
  u16* outpw = (u16*)alloc((size_t)D_ * D_ * 2);
  u16* w1b   = (u16*)alloc((size_t)4 * D_ * D_ * 2);
  u16* w2b   = (u16*)alloc((size_t)4 * D_ * D_ * 2);
  float* xs  = (float*)alloc((size_t)MROWS * D_ * 4);
  u16* hbuf  = (u16*)alloc((size_t)MROWS * D_ * 2);
  char* region = alloc((size_t)MROWS * 4 * D_ * 2);      // 64 MB: qkv(48)+obuf(16), reused by ff
  u16* qkvb = (u16*)region;
  u16* obuf = (u16*)(region + (size_t)MROWS * 3 * D_ * 2);
  u16* ffb  = (u16*)region;

  hipMemcpyAsync(d_out, (const void*)x, (size_t)B_ * T_ * D_ * 4, hipMemcpyDeviceToDevice, stream);
  hipMemsetAsync(auxacc, 0, 4, stream);

  router_kernel<<<B_ * T_ / 4, 256, 0, stream>>>(x, w_router, logits, auxacc);
  aux_fin<<<1, 1, 0, stream>>>(auxacc, out + (size_t)B_ * T_ * D_);
  rank_kernel<<<dim3(T_ / 256, B_), 256, 0, stream>>>(logits, mask);
  compact_kernel<<<B_, 64, 0, stream>>>(mask, idx);
  ln_kernel<true><<<MROWS, 256, 0, stream>>>(x, idx, ln1g, ln1b, xs, hbuf);

  f2bf_kernel<<<(3 * D_ * D_ / 4) / 256, 256, 0, stream>>>(in_proj_w, inpw, 3 * D_ * D_);
  f2bf_kernel<<<(D_ * D_ / 4) / 256, 256, 0, stream>>>(out_proj_w, outpw, D_ * D_);
  f2bf_kernel<<<(4 * D_ * D_ / 4) / 256, 256, 0, stream>>>(w1, w1b, 4 * D_ * D_);
  f2bf_kernel<<<(4 * D_ * D_ / 4) / 256, 256, 0, stream>>>(w2, w2b, 4 * D_ * D_);

  gemm_bt<0><<<dim3(3 * D_ / 128, MROWS / 128), 256, 0, stream>>>(
      hbuf, inpw, in_proj_b, nullptr, qkvb, nullptr, nullptr, MROWS, 3 * D_, D_);
  attn_kernel<<<dim3(KTOK / 128, B_ * H_), 256, 0, stream>>>(qkvb, obuf);
  gemm_bt<1><<<dim3(D_ / 128, MROWS / 128), 256, 0, stream>>>(
      obuf, outpw, out_proj_b, xs, nullptr, nullptr, nullptr, MROWS, D_, D_);
  ln_kernel<false><<<MROWS, 256, 0, stream>>>(xs, nullptr, ln2g, ln2b, nullptr, hbuf);
  gemm_bt<2><<<dim3(4 * D_ / 128, MROWS / 128), 256, 0, stream>>>(
      hbuf, w1b, b1, nullptr, ffb, nullptr, nullptr, MROWS, 4 * D_, D_);
  gemm_bt<3><<<dim3(D_ / 128, MROWS / 128), 256, 0, stream>>>(
      ffb, w2b, b2, xs, nullptr, out, idx, MROWS, D_, 4 * D_);
}

// Round 4
// 815.333 us; speedup vs baseline: 1.2034x; 1.0817x over previous
//
#include <hip/hip_runtime.h>

#define B_    4
#define T_    4096
#define D_    1024
#define H_    16
#define DH_   64
#define KTOK  2048
#define MROWS (B_*KTOK)   // 8192

typedef unsigned short u16;
typedef __attribute__((ext_vector_type(8))) short short8;
typedef __attribute__((ext_vector_type(4))) float f32x4;
typedef __attribute__((ext_vector_type(4))) unsigned int u32x4;
typedef __attribute__((ext_vector_type(2))) unsigned int u32x2;
typedef __attribute__((ext_vector_type(4))) unsigned short u16x4;

static __device__ __forceinline__ u16 f2bf(float f) {
  union { float f; unsigned int u; } a; a.f = f;
  unsigned int u = a.u;
  unsigned int r = (u + 0x7FFFu + ((u >> 16) & 1u)) >> 16;   // RNE
  return (u16)r;
}

#if defined(__has_builtin)
#if __has_builtin(__builtin_amdgcn_exp2f)
#define EXP2F(x) __builtin_amdgcn_exp2f(x)
#endif
#endif
#ifndef EXP2F
#define EXP2F(x) exp2f(x)
#endif

// pack two fp32 -> adjacent bf16 pair (low = a), RNE
static __device__ __forceinline__ unsigned int pkbf(float a, float b) {
  unsigned int ua = __builtin_bit_cast(unsigned int, a);
  unsigned int ub = __builtin_bit_cast(unsigned int, b);
  ua += 0x7FFFu + ((ua >> 16) & 1u);
  ub += 0x7FFFu + ((ub >> 16) & 1u);
  return __builtin_amdgcn_perm(ub, ua, 0x07060302u);  // [ua.hi16 low, ub.hi16 high]
}

static __device__ __forceinline__ void gld_lds16(const u16* g, u16* l) {
  __builtin_amdgcn_global_load_lds((__attribute__((address_space(1))) void*)g,
                                   (__attribute__((address_space(3))) void*)l, 16, 0, 0);
}

// ---------------- router: logits = x @ w_router, accumulate sum(logits^2) ----------------
__global__ void __launch_bounds__(256) router_kernel(const float* __restrict__ x,
    const float* __restrict__ wr, float* __restrict__ logits, float* __restrict__ auxacc)
{
  int tid = threadIdx.x; int lane = tid & 63, wave = tid >> 6;
  int row = blockIdx.x * 4 + wave;                 // 0 .. B*T-1
  const float* xr = x + (size_t)row * D_;
  float dot = 0.f;
#pragma unroll
  for (int j = 0; j < 4; j++) {
    int c = j * 256 + lane * 4;
    f32x4 xv = *(const f32x4*)(xr + c);
    f32x4 wv = *(const f32x4*)(wr + c);
    dot += xv[0]*wv[0] + xv[1]*wv[1] + xv[2]*wv[2] + xv[3]*wv[3];
  }
#pragma unroll
  for (int d = 1; d < 64; d <<= 1) dot += __shfl_xor(dot, d);
  __shared__ float red[4];
  if (lane == 0) { logits[row] = dot; red[wave] = dot; }
  __syncthreads();
  if (tid == 0) {
    float a = red[0]*red[0] + red[1]*red[1] + red[2]*red[2] + red[3]*red[3];
    atomicAdd(auxacc, a);
  }
}

__global__ void aux_fin(const float* __restrict__ acc, float* __restrict__ out)
{
  out[0] = acc[0] * (0.01f / (float)(B_ * T_));
}

// ---------------- rank: selected iff #{better} < KTOK ----------------
__global__ void __launch_bounds__(256) rank_kernel(const float* __restrict__ logits, int* __restrict__ mask)
{
  __shared__ float ll[T_];
  int b = blockIdx.y;
  int tid = threadIdx.x;
  const float* lg = logits + (size_t)b * T_;
  for (int j = tid; j < T_; j += 256) ll[j] = lg[j];
  __syncthreads();
  int t = blockIdx.x * 256 + tid;
  float my = ll[t];
  int rank = 0;
  for (int j = 0; j < T_; j += 4) {
    f32x4 lj = *(const f32x4*)&ll[j];
    rank += (lj[0] > my) || (lj[0] == my && (j+0) < t);
    rank += (lj[1] > my) || (lj[1] == my && (j+1) < t);
    rank += (lj[2] > my) || (lj[2] == my && (j+2) < t);
    rank += (lj[3] > my) || (lj[3] == my && (j+3) < t);
  }
  mask[(size_t)b * T_ + t] = (rank < KTOK) ? 1 : 0;
}

// ---------------- compact selected token ids (ascending) ----------------
__global__ void __launch_bounds__(64) compact_kernel(const int* __restrict__ mask, int* __restrict__ idx)
{
  int b = blockIdx.x; int lane = threadIdx.x;
  int base = 0;
  for (int c = 0; c < T_; c += 64) {
    int t = c + lane;
    int m = mask[(size_t)b * T_ + t];
    unsigned long long bal = __ballot(m != 0);
    int pref = __popcll(bal & ((1ull << lane) - 1ull));
    if (m) idx[b * KTOK + base + pref] = t;
    base += __popcll(bal);
  }
}

// ---------------- LayerNorm (optionally gathering rows of x via idx) ----------------
template<bool GATHER>
__global__ void __launch_bounds__(256) ln_kernel(const float* __restrict__ src,
    const int* __restrict__ idx, const float* __restrict__ g, const float* __restrict__ bb,
    float* __restrict__ xs_out, u16* __restrict__ hout)
{
  int row = blockIdx.x;
  int tid = threadIdx.x;
  const float* srow;
  if (GATHER) {
    int b = row >> 11, i = row & (KTOK - 1);
    int t = idx[b * KTOK + i];
    srow = src + ((size_t)b * T_ + t) * D_;
  } else {
    srow = src + (size_t)row * D_;
  }
  f32x4 v = *(const f32x4*)(srow + tid * 4);
  float s  = v[0] + v[1] + v[2] + v[3];
  float sq = v[0]*v[0] + v[1]*v[1] + v[2]*v[2] + v[3]*v[3];
#pragma unroll
  for (int d = 1; d < 64; d <<= 1) { s += __shfl_xor(s, d); sq += __shfl_xor(sq, d); }
  __shared__ float rs[4], rq[4];
  int lane = tid & 63, wave = tid >> 6;
  if (lane == 0) { rs[wave] = s; rq[wave] = sq; }
  __syncthreads();
  s  = rs[0] + rs[1] + rs[2] + rs[3];
  sq = rq[0] + rq[1] + rq[2] + rq[3];
  float mean = s * (1.0f / D_);
  float var  = sq * (1.0f / D_) - mean * mean;
  float rstd = rsqrtf(var + 1e-5f);
  f32x4 gg = *(const f32x4*)(g + tid * 4);
  f32x4 bv = *(const f32x4*)(bb + tid * 4);
  if (GATHER) *(f32x4*)(xs_out + (size_t)row * D_ + tid * 4) = v;
  u16x4 o;
#pragma unroll
  for (int j = 0; j < 4; j++) o[j] = f2bf((v[j] - mean) * rstd * gg[j] + bv[j]);
  *(u16x4*)(hout + (size_t)row * D_ + tid * 4) = o;
}

// ---------------- fp32 -> bf16 weight convert ----------------
__global__ void __launch_bounds__(256) f2bf_kernel(const float* __restrict__ s, u16* __restrict__ d, int n)
{
  int i = (blockIdx.x * 256 + threadIdx.x) * 4;
  if (i < n) {
    f32x4 v = *(const f32x4*)(s + i);
    u16x4 o; o[0]=f2bf(v[0]); o[1]=f2bf(v[1]); o[2]=f2bf(v[2]); o[3]=f2bf(v[3]);
    *(u16x4*)(d + i) = o;
  }
}

// ---------------- GEMM: C[M,N] = A[M,K](bf16) @ W[N,K]^T(bf16) + bias, fused epilogues --------
template<int EPI>
__global__ void __launch_bounds__(256, 2) gemm_bt(
    const u16* __restrict__ A, const u16* __restrict__ W,
    const float* __restrict__ bias, float* __restrict__ xs,
    u16* __restrict__ Cb, float* __restrict__ outf,
    const int* __restrict__ idx, int M, int N, int K)
{
  __shared__ u16 As[128 * 32];
  __shared__ u16 Ws[128 * 32];
  const int tid = threadIdx.x;
  const int lane = tid & 63, wave = tid >> 6;
  const int wm = wave >> 1, wn = wave & 1;
  const int m16 = lane & 15, quad = lane >> 4;

  const size_t arow0 = (size_t)blockIdx.y * 128;
  const size_t wrow0 = (size_t)blockIdx.x * 128;
  const int r4 = lane >> 2, c8 = (lane & 3) * 8;

  const u16* ag0 = A + (arow0 + wave * 16 + r4) * (size_t)K + c8;
  const u16* ag1 = ag0 + (size_t)64 * K;
  const u16* wg0 = W + (wrow0 + wave * 16 + r4) * (size_t)K + c8;
  const u16* wg1 = wg0 + (size_t)64 * K;
  u16* la0 = As + (wave * 16) * 32;
  u16* la1 = As + (64 + wave * 16) * 32;
  u16* lw0 = Ws + (wave * 16) * 32;
  u16* lw1 = Ws + (64 + wave * 16) * 32;

  f32x4 acc[4][4];
#pragma unroll
  for (int i = 0; i < 4; i++)
#pragma unroll
    for (int j = 0; j < 4; j++) acc[i][j] = (f32x4)0.0f;

  for (int k0 = 0; k0 < K; k0 += 32) {
    gld_lds16(ag0 + k0, la0);
    gld_lds16(ag1 + k0, la1);
    gld_lds16(wg0 + k0, lw0);
    gld_lds16(wg1 + k0, lw1);
    __syncthreads();
    short8 af[4], wf[4];
#pragma unroll
    for (int mt = 0; mt < 4; mt++)
      af[mt] = *(const short8*)(As + (wm * 64 + mt * 16 + m16) * 32 + quad * 8);
#pragma unroll
    for (int nt = 0; nt < 4; nt++)
      wf[nt] = *(const short8*)(Ws + (wn * 64 + nt * 16 + m16) * 32 + quad * 8);
#pragma unroll
    for (int mt = 0; mt < 4; mt++)
#pragma unroll
      for (int nt = 0; nt < 4; nt++)
        acc[mt][nt] = __builtin_amdgcn_mfma_f32_16x16x32_bf16(af[mt], wf[nt], acc[mt][nt], 0, 0, 0);
    __syncthreads();
  }

#pragma unroll
  for (int mt = 0; mt < 4; mt++) {
#pragma unroll
    for (int nt = 0; nt < 4; nt++) {
      f32x4 a = acc[mt][nt];
      size_t col = wrow0 + wn * 64 + nt * 16 + m16;
      float bvv = bias[col];
#pragma unroll
      for (int r = 0; r < 4; r++) {
        size_t row = arow0 + wm * 64 + mt * 16 + quad * 4 + r;
        float v = a[r] + bvv;
        if (EPI == 0) {
          Cb[row * (size_t)N + col] = f2bf(v);
        } else if (EPI == 1) {
          size_t o = row * (size_t)N + col;
          xs[o] = xs[o] + v;
        } else if (EPI == 2) {
          float gv = 0.5f * v * (1.0f + erff(v * 0.70710678118654752f));
          Cb[row * (size_t)N + col] = f2bf(gv);
        } else {
          int b = (int)(row >> 11);
          int i = (int)(row & (KTOK - 1));
          int t = idx[b * KTOK + i];
          float vv = xs[row * (size_t)D_ + col] + v;
          outf[((size_t)b * T_ + t) * D_ + col] = vv;
        }
      }
    }
  }
}

// ---------------- flash attention v3: S^T orientation, no online max ----------------
// Ks: [key][dh]   stride 72 u16 (padded)
// Vt: [dh][key]   stride 88 u16, b64-block XOR swizzle kb^((dh>>2)&14)
// Ps: per-wave [q 0..15][key 0..63] stride 72 u16 (reused for qh=0,1 sequentially)
// S^T = mfma(A=K, B=Q): lane holds q = m16 (fixed), keys nt*16 + quad*4 + r
//   -> softmax entirely in-lane, P packs to b64 stores, A-frag reads are b128.
#define PSTR 72
__global__ void __launch_bounds__(256, 4) attn_kernel(const u16* __restrict__ qkv,
                                                      u16* __restrict__ obuf)
{
  __shared__ u16 Ks[64 * 72];        // 9216 B
  __shared__ u16 Vt[64 * 88];        // 11264 B
  __shared__ u16 Ps[4][16 * PSTR];   // 9216 B

  const int tid = threadIdx.x;
  const int lane = tid & 63, wave = tid >> 6;
  const int m16 = lane & 15, quad = lane >> 4;
  const int bh = blockIdx.y;
  const int b = bh >> 4, h = bh & 15;
  const int q0 = blockIdx.x * 128 + wave * 32;     // this wave: q0..q0+31

  const u16* base = qkv + ((size_t)b * KTOK) * (3 * D_) + h * DH_;

  // Q fragments (loaded once); B-operand: lane n=m16 = q-local
  short8 qf[2][2];
#pragma unroll
  for (int qh = 0; qh < 2; qh++) {
    const u16* qrow = base + (size_t)(q0 + qh * 16 + m16) * (3 * D_);
    qf[qh][0] = *(const short8*)(qrow + quad * 8);
    qf[qh][1] = *(const short8*)(qrow + 32 + quad * 8);
  }

  f32x4 oacc[2][4];
#pragma unroll
  for (int qh = 0; qh < 2; qh++)
#pragma unroll
    for (int nt = 0; nt < 4; nt++) oacc[qh][nt] = (f32x4)0.0f;
  f32x4 lsum[2] = {(f32x4)0.0f, (f32x4)0.0f};

  const float cexp = 0.18033688f;    // log2(e) / 8

  for (int tk = 0; tk < KTOK; tk += 64) {
    __syncthreads();
    // ---- stage K: 256 threads, key=tid>>2, dof=(tid&3)*16 ----
    {
      int key = tid >> 2, dof = (tid & 3) * 16;
      const u16* krow = base + (size_t)(tk + key) * (3 * D_) + D_ + dof;
      *(u32x4*)&Ks[key * 72 + dof]     = *(const u32x4*)krow;
      *(u32x4*)&Ks[key * 72 + dof + 8] = *(const u32x4*)(krow + 8);
    }
    // ---- stage V transposed: wave w loads keys tk+16w..+15, lane = dh ----
    {
      u16 vv[16];
      const u16* vp = base + (size_t)(tk + wave * 16) * (3 * D_) + 2 * D_ + lane;
#pragma unroll
      for (int i = 0; i < 16; i++) vv[i] = vp[(size_t)i * 3 * D_];
      int sw = (lane >> 2) & 14;
#pragma unroll
      for (int c = 0; c < 4; c++) {
        int kb = wave * 4 + c;
        u16x4 pk; pk[0] = vv[4*c]; pk[1] = vv[4*c+1]; pk[2] = vv[4*c+2]; pk[3] = vv[4*c+3];
        *(u16x4*)&Vt[lane * 88 + (kb ^ sw) * 4] = pk;
      }
    }
    __syncthreads();

    // ---- S^T = K Q^T: D[m=key_local][n=q_local] ----
    f32x4 sacc[2][4];
#pragma unroll
    for (int qh = 0; qh < 2; qh++)
#pragma unroll
      for (int nt = 0; nt < 4; nt++) sacc[qh][nt] = (f32x4)0.0f;
#pragma unroll
    for (int nt = 0; nt < 4; nt++) {
      short8 kf0 = *(const short8*)&Ks[(nt * 16 + m16) * 72 + quad * 8];
      short8 kf1 = *(const short8*)&Ks[(nt * 16 + m16) * 72 + 32 + quad * 8];
#pragma unroll
      for (int qh = 0; qh < 2; qh++) {
        sacc[qh][nt] = __builtin_amdgcn_mfma_f32_16x16x32_bf16(kf0, qf[qh][0], sacc[qh][nt], 0, 0, 0);
        sacc[qh][nt] = __builtin_amdgcn_mfma_f32_16x16x32_bf16(kf1, qf[qh][1], sacc[qh][nt], 0, 0, 0);
      }
    }

    // ---- per qh: exp2, accumulate l, pack P -> LDS, read A-frags, PV ----
#pragma unroll
    for (int qh = 0; qh < 2; qh++) {
#pragma unroll
      for (int nt = 0; nt < 4; nt++) {
        f32x4 p;
#pragma unroll
        for (int r = 0; r < 4; r++) p[r] = EXP2F(sacc[qh][nt][r] * cexp);
        lsum[qh] += p;
        u32x2 w2; w2[0] = pkbf(p[0], p[1]); w2[1] = pkbf(p[2], p[3]);
        *(u32x2*)&Ps[wave][m16 * PSTR + nt * 16 + quad * 4] = w2;
      }
      short8 pa0 = *(const short8*)&Ps[wave][m16 * PSTR + quad * 8];
      short8 pa1 = *(const short8*)&Ps[wave][m16 * PSTR + 32 + quad * 8];
#pragma unroll
      for (int nt = 0; nt < 4; nt++) {
        int dh = nt * 16 + m16;
        int sw = (dh >> 2) & 14;
        short8 vf0 = *(const short8*)&Vt[dh * 88 + ((2 * quad) ^ sw) * 4];
        short8 vf1 = *(const short8*)&Vt[dh * 88 + ((8 + 2 * quad) ^ sw) * 4];
        oacc[qh][nt] = __builtin_amdgcn_mfma_f32_16x16x32_bf16(pa0, vf0, oacc[qh][nt], 0, 0, 0);
        oacc[qh][nt] = __builtin_amdgcn_mfma_f32_16x16x32_bf16(pa1, vf1, oacc[qh][nt], 0, 0, 0);
      }
    }
  }

  // ---- final l reduction: in-lane horizontal + cross-quad (xor16, xor32) ----
  float rl[2][4];
#pragma unroll
  for (int qh = 0; qh < 2; qh++) {
    float l = (lsum[qh][0] + lsum[qh][1]) + (lsum[qh][2] + lsum[qh][3]);
    l += __shfl_xor(l, 16);
    l += __shfl_xor(l, 32);
    // now every lane holds l for q = its m16; redistribute to q=quad*4+r
#pragma unroll
    for (int r = 0; r < 4; r++) {
      float lr = __shfl(l, (lane & 48) | (quad * 4 + r));
      rl[qh][r] = 1.0f / lr;
    }
  }

  // ---- epilogue: O rows q=quad*4+r, cols dh=nt*16+m16 ----
#pragma unroll
  for (int qh = 0; qh < 2; qh++)
#pragma unroll
    for (int nt = 0; nt < 4; nt++)
#pragma unroll
      for (int r = 0; r < 4; r++) {
        int qq = q0 + qh * 16 + quad * 4 + r;
        float v = oacc[qh][nt][r] * rl[qh][r];
        obuf[((size_t)b * KTOK + qq) * D_ + h * DH_ + nt * 16 + m16] = f2bf(v);
      }
}

// ---------------- launch ----------------
extern "C" void kernel_launch(void* const* d_in, const int* in_sizes, int n_in,
                              void* d_out, int out_size, void* d_ws, size_t ws_size,
                              hipStream_t stream)
{
  (void)in_sizes; (void)n_in; (void)out_size; (void)ws_size;
  const float* x          = (const float*)d_in[0];
  const float* w_router   = (const float*)d_in[1];
  const float* in_proj_w  = (const float*)d_in[2];
  const float* in_proj_b  = (const float*)d_in[3];
  const float* out_proj_w = (const float*)d_in[4];
  const float* out_proj_b = (const float*)d_in[5];
  const float* w1         = (const float*)d_in[6];
  const float* b1         = (const float*)d_in[7];
  const float* w2         = (const float*)d_in[8];
  const float* b2         = (const float*)d_in[9];
  const float* ln1g       = (const float*)d_in[10];
  const float* ln1b       = (const float*)d_in[11];
  const float* ln2g       = (const float*)d_in[12];
  const float* ln2b       = (const float*)d_in[13];
  float* out = (float*)d_out;

  char* w = (char*)d_ws;
  auto alloc = [&](size_t bytes) -> char* {
    char* p = w; w += (bytes + 255) & ~(size_t)255; return p;
  };
  float* logits = (float*)alloc((size_t)B_ * T_ * 4);
  int*   mask   = (int*)  alloc((size_t)B_ * T_ * 4);
  int*   idx    = (int*)  alloc((size_t)B_ * KTOK * 4);
  float* auxacc = (float*)alloc(256);
  u16* inpw  = (u16*)alloc((size_t)3 * D_ * D_ * 2);
  u16* outpw = (u16*)alloc((size_t)D_ * D_ * 2);
  u16* w1b   = (u16*)alloc((size_t)4 * D_ * D_ * 2);
  u16* w2b   = (u16*)alloc((size_t)4 * D_ * D_ * 2);
  float* xs  = (float*)alloc((size_t)MROWS * D_ * 4);
  u16* hbuf  = (u16*)alloc((size_t)MROWS * D_ * 2);
  char* region = alloc((size_t)MROWS * 4 * D_ * 2);      // 64 MB: qkv(48)+obuf(16), reused by ff
  u16* qkvb = (u16*)region;
  u16* obuf = (u16*)(region + (size_t)MROWS * 3 * D_ * 2);
  u16* ffb  = (u16*)region;

  (void)hipMemcpyAsync(d_out, (const void*)x, (size_t)B_ * T_ * D_ * 4, hipMemcpyDeviceToDevice, stream);
  (void)hipMemsetAsync(auxacc, 0, 4, stream);

  router_kernel<<<B_ * T_ / 4, 256, 0, stream>>>(x, w_router, logits, auxacc);
  aux_fin<<<1, 1, 0, stream>>>(auxacc, out + (size_t)B_ * T_ * D_);
  rank_kernel<<<dim3(T_ / 256, B_), 256, 0, stream>>>(logits, mask);
  compact_kernel<<<B_, 64, 0, stream>>>(mask, idx);
  ln_kernel<true><<<MROWS, 256, 0, stream>>>(x, idx, ln1g, ln1b, xs, hbuf);

  f2bf_kernel<<<(3 * D_ * D_ / 4) / 256, 256, 0, stream>>>(in_proj_w, inpw, 3 * D_ * D_);
  f2bf_kernel<<<(D_ * D_ / 4) / 256, 256, 0, stream>>>(out_proj_w, outpw, D_ * D_);
  f2bf_kernel<<<(4 * D_ * D_ / 4) / 256, 256, 0, stream>>>(w1, w1b, 4 * D_ * D_);
  f2bf_kernel<<<(4 * D_ * D_ / 4) / 256, 256, 0, stream>>>(w2, w2b, 4 * D_ * D_);

  gemm_bt<0><<<dim3(3 * D_ / 128, MROWS / 128), 256, 0, stream>>>(
      hbuf, inpw, in_proj_b, nullptr, qkvb, nullptr, nullptr, MROWS, 3 * D_, D_);
  attn_kernel<<<dim3(KTOK / 128, B_ * H_), 256, 0, stream>>>(qkvb, obuf);
  gemm_bt<1><<<dim3(D_ / 128, MROWS / 128), 256, 0, stream>>>(
      obuf, outpw, out_proj_b, xs, nullptr, nullptr, nullptr, MROWS, D_, D_);
  ln_kernel<false><<<MROWS, 256, 0, stream>>>(xs, nullptr, ln2g, ln2b, nullptr, hbuf);
  gemm_bt<2><<<dim3(4 * D_ / 128, MROWS / 128), 256, 0, stream>>>(
      hbuf, w1b, b1, nullptr, ffb, nullptr, nullptr, MROWS, 4 * D_, D_);
  gemm_bt<3><<<dim3(D_ / 128, MROWS / 128), 256, 0, stream>>>(
      ffb, w2b, b2, xs, nullptr, out, idx, MROWS, D_, 4 * D_);
}

// Round 5
// 797.252 us; speedup vs baseline: 1.2307x; 1.0227x over previous
//
#include <hip/hip_runtime.h>

#define B_    4
#define T_    4096
#define D_    1024
#define H_    16
#define DH_   64
#define KTOK  2048
#define MROWS (B_*KTOK)   // 8192

typedef unsigned short u16;
typedef __attribute__((ext_vector_type(8))) short short8;
typedef __attribute__((ext_vector_type(4))) float f32x4;
typedef __attribute__((ext_vector_type(4))) unsigned int u32x4;
typedef __attribute__((ext_vector_type(2))) unsigned int u32x2;
typedef __attribute__((ext_vector_type(4))) unsigned short u16x4;

static __device__ __forceinline__ u16 f2bf(float f) {
  union { float f; unsigned int u; } a; a.f = f;
  unsigned int u = a.u;
  unsigned int r = (u + 0x7FFFu + ((u >> 16) & 1u)) >> 16;   // RNE
  return (u16)r;
}

#if defined(__has_builtin)
#if __has_builtin(__builtin_amdgcn_exp2f)
#define EXP2F(x) __builtin_amdgcn_exp2f(x)
#endif
#endif
#ifndef EXP2F
#define EXP2F(x) exp2f(x)
#endif

// pack two fp32 -> adjacent bf16 pair (low = a), TRUNCATING (1 v_perm).
// P feeds PV whose softmax denominator carries the same bias -> cancels.
static __device__ __forceinline__ unsigned int pkbf_t(float a, float b) {
  unsigned int ua = __builtin_bit_cast(unsigned int, a);
  unsigned int ub = __builtin_bit_cast(unsigned int, b);
  return __builtin_amdgcn_perm(ub, ua, 0x07060302u);  // [ua.hi16 low, ub.hi16 high]
}

static __device__ __forceinline__ void gld_lds16(const u16* g, u16* l) {
  __builtin_amdgcn_global_load_lds((__attribute__((address_space(1))) void*)g,
                                   (__attribute__((address_space(3))) void*)l, 16, 0, 0);
}

// ---------------- router: logits = x @ w_router, accumulate sum(logits^2) ----------------
__global__ void __launch_bounds__(256) router_kernel(const float* __restrict__ x,
    const float* __restrict__ wr, float* __restrict__ logits, float* __restrict__ auxacc)
{
  int tid = threadIdx.x; int lane = tid & 63, wave = tid >> 6;
  int row = blockIdx.x * 4 + wave;                 // 0 .. B*T-1
  const float* xr = x + (size_t)row * D_;
  float dot = 0.f;
#pragma unroll
  for (int j = 0; j < 4; j++) {
    int c = j * 256 + lane * 4;
    f32x4 xv = *(const f32x4*)(xr + c);
    f32x4 wv = *(const f32x4*)(wr + c);
    dot += xv[0]*wv[0] + xv[1]*wv[1] + xv[2]*wv[2] + xv[3]*wv[3];
  }
#pragma unroll
  for (int d = 1; d < 64; d <<= 1) dot += __shfl_xor(dot, d);
  __shared__ float red[4];
  if (lane == 0) { logits[row] = dot; red[wave] = dot; }
  __syncthreads();
  if (tid == 0) {
    float a = red[0]*red[0] + red[1]*red[1] + red[2]*red[2] + red[3]*red[3];
    atomicAdd(auxacc, a);
  }
}

// ---------------- rank: selected iff #{better} < KTOK ----------------
__global__ void __launch_bounds__(256) rank_kernel(const float* __restrict__ logits, int* __restrict__ mask)
{
  __shared__ float ll[T_];
  int b = blockIdx.y;
  int tid = threadIdx.x;
  const float* lg = logits + (size_t)b * T_;
  for (int j = tid; j < T_; j += 256) ll[j] = lg[j];
  __syncthreads();
  int t = blockIdx.x * 256 + tid;
  float my = ll[t];
  int rank = 0;
  for (int j = 0; j < T_; j += 4) {
    f32x4 lj = *(const f32x4*)&ll[j];
    rank += (lj[0] > my) || (lj[0] == my && (j+0) < t);
    rank += (lj[1] > my) || (lj[1] == my && (j+1) < t);
    rank += (lj[2] > my) || (lj[2] == my && (j+2) < t);
    rank += (lj[3] > my) || (lj[3] == my && (j+3) < t);
  }
  mask[(size_t)b * T_ + t] = (rank < KTOK) ? 1 : 0;
}

// ---------------- compact selected token ids (ascending); also finalize aux ----------------
__global__ void __launch_bounds__(64) compact_kernel(const int* __restrict__ mask, int* __restrict__ idx,
                                                     const float* __restrict__ acc, float* __restrict__ auxout)
{
  int b = blockIdx.x; int lane = threadIdx.x;
  if (b == 0 && lane == 0) auxout[0] = acc[0] * (0.01f / (float)(B_ * T_));
  int base = 0;
  for (int c = 0; c < T_; c += 64) {
    int t = c + lane;
    int m = mask[(size_t)b * T_ + t];
    unsigned long long bal = __ballot(m != 0);
    int pref = __popcll(bal & ((1ull << lane) - 1ull));
    if (m) idx[b * KTOK + base + pref] = t;
    base += __popcll(bal);
  }
}

// ---------------- LayerNorm (optionally gathering rows of x via idx) ----------------
template<bool GATHER>
__global__ void __launch_bounds__(256) ln_kernel(const float* __restrict__ src,
    const int* __restrict__ idx, const float* __restrict__ g, const float* __restrict__ bb,
    float* __restrict__ xs_out, u16* __restrict__ hout)
{
  int row = blockIdx.x;
  int tid = threadIdx.x;
  const float* srow;
  if (GATHER) {
    int b = row >> 11, i = row & (KTOK - 1);
    int t = idx[b * KTOK + i];
    srow = src + ((size_t)b * T_ + t) * D_;
  } else {
    srow = src + (size_t)row * D_;
  }
  f32x4 v = *(const f32x4*)(srow + tid * 4);
  float s  = v[0] + v[1] + v[2] + v[3];
  float sq = v[0]*v[0] + v[1]*v[1] + v[2]*v[2] + v[3]*v[3];
#pragma unroll
  for (int d = 1; d < 64; d <<= 1) { s += __shfl_xor(s, d); sq += __shfl_xor(sq, d); }
  __shared__ float rs[4], rq[4];
  int lane = tid & 63, wave = tid >> 6;
  if (lane == 0) { rs[wave] = s; rq[wave] = sq; }
  __syncthreads();
  s  = rs[0] + rs[1] + rs[2] + rs[3];
  sq = rq[0] + rq[1] + rq[2] + rq[3];
  float mean = s * (1.0f / D_);
  float var  = sq * (1.0f / D_) - mean * mean;
  float rstd = rsqrtf(var + 1e-5f);
  f32x4 gg = *(const f32x4*)(g + tid * 4);
  f32x4 bv = *(const f32x4*)(bb + tid * 4);
  if (GATHER) *(f32x4*)(xs_out + (size_t)row * D_ + tid * 4) = v;
  u16x4 o;
#pragma unroll
  for (int j = 0; j < 4; j++) o[j] = f2bf((v[j] - mean) * rstd * gg[j] + bv[j]);
  *(u16x4*)(hout + (size_t)row * D_ + tid * 4) = o;
}

// ---------------- fp32 -> bf16 convert, all 4 weight matrices in one dispatch ----------------
__global__ void __launch_bounds__(256) f2bf_all(const float* __restrict__ s0, const float* __restrict__ s1,
    const float* __restrict__ s2, const float* __restrict__ s3,
    u16* __restrict__ d0, u16* __restrict__ d1, u16* __restrict__ d2, u16* __restrict__ d3)
{
  const size_t c0 = (size_t)3 * D_ * D_, c1 = (size_t)4 * D_ * D_, c2 = (size_t)8 * D_ * D_;
  size_t e = (size_t)blockIdx.x * 1024 + (size_t)threadIdx.x * 4;
  const float* s; u16* d; size_t off;
  if (e < c0)      { s = s0; d = d0; off = e; }
  else if (e < c1) { s = s1; d = d1; off = e - c0; }
  else if (e < c2) { s = s2; d = d2; off = e - c1; }
  else             { s = s3; d = d3; off = e - c2; }
  f32x4 v = *(const f32x4*)(s + off);
  u16x4 o; o[0]=f2bf(v[0]); o[1]=f2bf(v[1]); o[2]=f2bf(v[2]); o[3]=f2bf(v[3]);
  *(u16x4*)(d + off) = o;
}

// ---------------- GEMM: C[M,N] = A[M,K](bf16) @ W[N,K]^T(bf16) + bias, fused epilogues --------
// EPI 0: write bf16 to Cb; Q columns (col<D) pre-scaled by log2(e)/8 for attention
// EPI 1: v += xs (fp32 residual), write fp32 to xs (in place)
// EPI 2: exact gelu, write bf16 to Cb
// EPI 3: v += xs residual, scatter-write fp32 rows into outf at token idx
template<int EPI>
__global__ void __launch_bounds__(256, 2) gemm_bt(
    const u16* __restrict__ A, const u16* __restrict__ W,
    const float* __restrict__ bias, float* __restrict__ xs,
    u16* __restrict__ Cb, float* __restrict__ outf,
    const int* __restrict__ idx, int M, int N, int K)
{
  __shared__ u16 As[128 * 32];
  __shared__ u16 Ws[128 * 32];
  const int tid = threadIdx.x;
  const int lane = tid & 63, wave = tid >> 6;
  const int wm = wave >> 1, wn = wave & 1;
  const int m16 = lane & 15, quad = lane >> 4;

  const size_t arow0 = (size_t)blockIdx.y * 128;
  const size_t wrow0 = (size_t)blockIdx.x * 128;
  const int r4 = lane >> 2, c8 = (lane & 3) * 8;

  const u16* ag0 = A + (arow0 + wave * 16 + r4) * (size_t)K + c8;
  const u16* ag1 = ag0 + (size_t)64 * K;
  const u16* wg0 = W + (wrow0 + wave * 16 + r4) * (size_t)K + c8;
  const u16* wg1 = wg0 + (size_t)64 * K;
  u16* la0 = As + (wave * 16) * 32;
  u16* la1 = As + (64 + wave * 16) * 32;
  u16* lw0 = Ws + (wave * 16) * 32;
  u16* lw1 = Ws + (64 + wave * 16) * 32;

  f32x4 acc[4][4];
#pragma unroll
  for (int i = 0; i < 4; i++)
#pragma unroll
    for (int j = 0; j < 4; j++) acc[i][j] = (f32x4)0.0f;

  for (int k0 = 0; k0 < K; k0 += 32) {
    gld_lds16(ag0 + k0, la0);
    gld_lds16(ag1 + k0, la1);
    gld_lds16(wg0 + k0, lw0);
    gld_lds16(wg1 + k0, lw1);
    __syncthreads();
    short8 af[4], wf[4];
#pragma unroll
    for (int mt = 0; mt < 4; mt++)
      af[mt] = *(const short8*)(As + (wm * 64 + mt * 16 + m16) * 32 + quad * 8);
#pragma unroll
    for (int nt = 0; nt < 4; nt++)
      wf[nt] = *(const short8*)(Ws + (wn * 64 + nt * 16 + m16) * 32 + quad * 8);
#pragma unroll
    for (int mt = 0; mt < 4; mt++)
#pragma unroll
      for (int nt = 0; nt < 4; nt++)
        acc[mt][nt] = __builtin_amdgcn_mfma_f32_16x16x32_bf16(af[mt], wf[nt], acc[mt][nt], 0, 0, 0);
    __syncthreads();
  }

#pragma unroll
  for (int mt = 0; mt < 4; mt++) {
#pragma unroll
    for (int nt = 0; nt < 4; nt++) {
      f32x4 a = acc[mt][nt];
      size_t col = wrow0 + wn * 64 + nt * 16 + m16;
      float bvv = bias[col];
#pragma unroll
      for (int r = 0; r < 4; r++) {
        size_t row = arow0 + wm * 64 + mt * 16 + quad * 4 + r;
        float v = a[r] + bvv;
        if (EPI == 0) {
          if (col < D_) v *= 0.18033688f;    // fold 1/sqrt(dh) * log2(e) into Q
          Cb[row * (size_t)N + col] = f2bf(v);
        } else if (EPI == 1) {
          size_t o = row * (size_t)N + col;
          xs[o] = xs[o] + v;
        } else if (EPI == 2) {
          float gv = 0.5f * v * (1.0f + erff(v * 0.70710678118654752f));
          Cb[row * (size_t)N + col] = f2bf(gv);
        } else {
          int b = (int)(row >> 11);
          int i = (int)(row & (KTOK - 1));
          int t = idx[b * KTOK + i];
          float vv = xs[row * (size_t)D_ + col] + v;
          outf[((size_t)b * T_ + t) * D_ + col] = vv;
        }
      }
    }
  }
}

// ---------------- flash attention v4: S^T orientation, no online max, hoisted vf ----------------
// Ks: [key][dh]   stride 72 u16 (padded)
// Vt: [dh][key]   stride 88 u16, b64-block XOR swizzle kb^((dh>>2)&14)
// Ps: per-wave [q 0..15][key 0..63] stride 72 u16 (reused for qh=0,1 sequentially)
// S^T = mfma(A=K, B=Q): lane holds q = m16 (fixed), keys nt*16 + quad*4 + r.
// Q arrives pre-scaled by log2(e)/8, so P = exp2(sacc) directly.
#define PSTR 72
__global__ void __launch_bounds__(256, 3) attn_kernel(const u16* __restrict__ qkv,
                                                      u16* __restrict__ obuf)
{
  __shared__ u16 Ks[64 * 72];        // 9216 B
  __shared__ u16 Vt[64 * 88];        // 11264 B
  __shared__ u16 Ps[4][16 * PSTR];   // 9216 B

  const int tid = threadIdx.x;
  const int lane = tid & 63, wave = tid >> 6;
  const int m16 = lane & 15, quad = lane >> 4;
  const int bh = blockIdx.y;
  const int b = bh >> 4, h = bh & 15;
  const int q0 = blockIdx.x * 128 + wave * 32;     // this wave: q0..q0+31

  const u16* base = qkv + ((size_t)b * KTOK) * (3 * D_) + h * DH_;

  // Q fragments (loaded once); B-operand: lane n=m16 = q-local
  short8 qf[2][2];
#pragma unroll
  for (int qh = 0; qh < 2; qh++) {
    const u16* qrow = base + (size_t)(q0 + qh * 16 + m16) * (3 * D_);
    qf[qh][0] = *(const short8*)(qrow + quad * 8);
    qf[qh][1] = *(const short8*)(qrow + 32 + quad * 8);
  }

  f32x4 oacc[2][4];
#pragma unroll
  for (int qh = 0; qh < 2; qh++)
#pragma unroll
    for (int nt = 0; nt < 4; nt++) oacc[qh][nt] = (f32x4)0.0f;
  f32x4 lsum[2] = {(f32x4)0.0f, (f32x4)0.0f};

  for (int tk = 0; tk < KTOK; tk += 64) {
    __syncthreads();
    // ---- stage K: 256 threads, key=tid>>2, dof=(tid&3)*16 ----
    {
      int key = tid >> 2, dof = (tid & 3) * 16;
      const u16* krow = base + (size_t)(tk + key) * (3 * D_) + D_ + dof;
      *(u32x4*)&Ks[key * 72 + dof]     = *(const u32x4*)krow;
      *(u32x4*)&Ks[key * 72 + dof + 8] = *(const u32x4*)(krow + 8);
    }
    // ---- stage V transposed: wave w loads keys tk+16w..+15, lane = dh ----
    {
      u16 vv[16];
      const u16* vp = base + (size_t)(tk + wave * 16) * (3 * D_) + 2 * D_ + lane;
#pragma unroll
      for (int i = 0; i < 16; i++) vv[i] = vp[(size_t)i * 3 * D_];
      int swl = (lane >> 2) & 14;
#pragma unroll
      for (int c = 0; c < 4; c++) {
        int kb = wave * 4 + c;
        u16x4 pk; pk[0] = vv[4*c]; pk[1] = vv[4*c+1]; pk[2] = vv[4*c+2]; pk[3] = vv[4*c+3];
        *(u16x4*)&Vt[lane * 88 + (kb ^ swl) * 4] = pk;
      }
    }
    __syncthreads();

    // ---- S^T = K Q^T: D[m=key_local][n=q_local] ----
    f32x4 sacc[2][4];
#pragma unroll
    for (int qh = 0; qh < 2; qh++)
#pragma unroll
      for (int nt = 0; nt < 4; nt++) sacc[qh][nt] = (f32x4)0.0f;
#pragma unroll
    for (int nt = 0; nt < 4; nt++) {
      short8 kf0 = *(const short8*)&Ks[(nt * 16 + m16) * 72 + quad * 8];
      short8 kf1 = *(const short8*)&Ks[(nt * 16 + m16) * 72 + 32 + quad * 8];
#pragma unroll
      for (int qh = 0; qh < 2; qh++) {
        sacc[qh][nt] = __builtin_amdgcn_mfma_f32_16x16x32_bf16(kf0, qf[qh][0], sacc[qh][nt], 0, 0, 0);
        sacc[qh][nt] = __builtin_amdgcn_mfma_f32_16x16x32_bf16(kf1, qf[qh][1], sacc[qh][nt], 0, 0, 0);
      }
    }

    // ---- hoisted V B-fragments (shared across qh) ----
    short8 vf[4][2];
#pragma unroll
    for (int nt = 0; nt < 4; nt++) {
      int dh = nt * 16 + m16;
      int sw = (dh >> 2) & 14;
      vf[nt][0] = *(const short8*)&Vt[dh * 88 + ((2 * quad) ^ sw) * 4];
      vf[nt][1] = *(const short8*)&Vt[dh * 88 + ((8 + 2 * quad) ^ sw) * 4];
    }

    // ---- per qh: exp2, accumulate l, pack P -> LDS, read A-frags, PV ----
#pragma unroll
    for (int qh = 0; qh < 2; qh++) {
#pragma unroll
      for (int nt = 0; nt < 4; nt++) {
        f32x4 p;
#pragma unroll
        for (int r = 0; r < 4; r++) p[r] = EXP2F(sacc[qh][nt][r]);
        lsum[qh] += p;
        u32x2 w2; w2[0] = pkbf_t(p[0], p[1]); w2[1] = pkbf_t(p[2], p[3]);
        *(u32x2*)&Ps[wave][m16 * PSTR + nt * 16 + quad * 4] = w2;
      }
      short8 pa0 = *(const short8*)&Ps[wave][m16 * PSTR + quad * 8];
      short8 pa1 = *(const short8*)&Ps[wave][m16 * PSTR + 32 + quad * 8];
#pragma unroll
      for (int nt = 0; nt < 4; nt++) {
        oacc[qh][nt] = __builtin_amdgcn_mfma_f32_16x16x32_bf16(pa0, vf[nt][0], oacc[qh][nt], 0, 0, 0);
        oacc[qh][nt] = __builtin_amdgcn_mfma_f32_16x16x32_bf16(pa1, vf[nt][1], oacc[qh][nt], 0, 0, 0);
      }
    }
  }

  // ---- final l reduction: in-lane horizontal + cross-quad (xor16, xor32) ----
  float rl[2][4];
#pragma unroll
  for (int qh = 0; qh < 2; qh++) {
    float l = (lsum[qh][0] + lsum[qh][1]) + (lsum[qh][2] + lsum[qh][3]);
    l += __shfl_xor(l, 16);
    l += __shfl_xor(l, 32);
    // now every lane holds l for q = its m16; redistribute to q=quad*4+r
#pragma unroll
    for (int r = 0; r < 4; r++) {
      float lr = __shfl(l, (lane & 48) | (quad * 4 + r));
      rl[qh][r] = 1.0f / lr;
    }
  }

  // ---- epilogue: O rows q=quad*4+r, cols dh=nt*16+m16 ----
#pragma unroll
  for (int qh = 0; qh < 2; qh++)
#pragma unroll
    for (int nt = 0; nt < 4; nt++)
#pragma unroll
      for (int r = 0; r < 4; r++) {
        int qq = q0 + qh * 16 + quad * 4 + r;
        float v = oacc[qh][nt][r] * rl[qh][r];
        obuf[((size_t)b * KTOK + qq) * D_ + h * DH_ + nt * 16 + m16] = f2bf(v);
      }
}

// ---------------- launch ----------------
extern "C" void kernel_launch(void* const* d_in, const int* in_sizes, int n_in,
                              void* d_out, int out_size, void* d_ws, size_t ws_size,
                              hipStream_t stream)
{
  (void)in_sizes; (void)n_in; (void)out_size; (void)ws_size;
  const float* x          = (const float*)d_in[0];
  const float* w_router   = (const float*)d_in[1];
  const float* in_proj_w  = (const float*)d_in[2];
  const float* in_proj_b  = (const float*)d_in[3];
  const float* out_proj_w = (const float*)d_in[4];
  const float* out_proj_b = (const float*)d_in[5];
  const float* w1         = (const float*)d_in[6];
  const float* b1         = (const float*)d_in[7];
  const float* w2         = (const float*)d_in[8];
  const float* b2         = (const float*)d_in[9];
  const float* ln1g       = (const float*)d_in[10];
  const float* ln1b       = (const float*)d_in[11];
  const float* ln2g       = (const float*)d_in[12];
  const float* ln2b       = (const float*)d_in[13];
  float* out = (float*)d_out;

  char* w = (char*)d_ws;
  auto alloc = [&](size_t bytes) -> char* {
    char* p = w; w += (bytes + 255) & ~(size_t)255; return p;
  };
  float* logits = (float*)alloc((size_t)B_ * T_ * 4);
  int*   mask   = (int*)  alloc((size_t)B_ * T_ * 4);
  int*   idx    = (int*)  alloc((size_t)B_ * KTOK * 4);
  float* auxacc = (float*)alloc(256);
  u16* inpw  = (u16*)alloc((size_t)3 * D_ * D_ * 2);
  u16* outpw = (u16*)alloc((size_t)D_ * D_ * 2);
  u16* w1b   = (u16*)alloc((size_t)4 * D_ * D_ * 2);
  u16* w2b   = (u16*)alloc((size_t)4 * D_ * D_ * 2);
  float* xs  = (float*)alloc((size_t)MROWS * D_ * 4);
  u16* hbuf  = (u16*)alloc((size_t)MROWS * D_ * 2);
  char* region = alloc((size_t)MROWS * 4 * D_ * 2);      // 64 MB: qkv(48)+obuf(16), reused by ff
  u16* qkvb = (u16*)region;
  u16* obuf = (u16*)(region + (size_t)MROWS * 3 * D_ * 2);
  u16* ffb  = (u16*)region;

  (void)hipMemcpyAsync(d_out, (const void*)x, (size_t)B_ * T_ * D_ * 4, hipMemcpyDeviceToDevice, stream);
  (void)hipMemsetAsync(auxacc, 0, 4, stream);

  router_kernel<<<B_ * T_ / 4, 256, 0, stream>>>(x, w_router, logits, auxacc);
  rank_kernel<<<dim3(T_ / 256, B_), 256, 0, stream>>>(logits, mask);
  compact_kernel<<<B_, 64, 0, stream>>>(mask, idx, auxacc, out + (size_t)B_ * T_ * D_);
  ln_kernel<true><<<MROWS, 256, 0, stream>>>(x, idx, ln1g, ln1b, xs, hbuf);

  f2bf_all<<<12 * D_ * D_ / 1024, 256, 0, stream>>>(in_proj_w, out_proj_w, w1, w2,
                                                    inpw, outpw, w1b, w2b);

  gemm_bt<0><<<dim3(3 * D_ / 128, MROWS / 128), 256, 0, stream>>>(
      hbuf, inpw, in_proj_b, nullptr, qkvb, nullptr, nullptr, MROWS, 3 * D_, D_);
  attn_kernel<<<dim3(KTOK / 128, B_ * H_), 256, 0, stream>>>(qkvb, obuf);
  gemm_bt<1><<<dim3(D_ / 128, MROWS / 128), 256, 0, stream>>>(
      obuf, outpw, out_proj_b, xs, nullptr, nullptr, nullptr, MROWS, D_, D_);
  ln_kernel<false><<<MROWS, 256, 0, stream>>>(xs, nullptr, ln2g, ln2b, nullptr, hbuf);
  gemm_bt<2><<<dim3(4 * D_ / 128, MROWS / 128), 256, 0, stream>>>(
      hbuf, w1b, b1, nullptr, ffb, nullptr, nullptr, MROWS, 4 * D_, D_);
  gemm_bt<3><<<dim3(D_ / 128, MROWS / 128), 256, 0, stream>>>(
      ffb, w2b, b2, xs, nullptr, out, idx, MROWS, D_, 4 * D_);
}